// Round 1
// baseline (84.317 us; speedup 1.0000x reference)
//
#include <hip/hip_runtime.h>
#include <math.h>

#define TPB 256
#define CH 16           // ref chunks per direction
#define CS 512          // refs per chunk = 8192 / CH

// Kernel 1: for each query point, min squared distance over one chunk of refs.
// grid = (N/TPB, CH, 2).  dir 0: query=pred, ref=label.  dir 1: swapped.
__global__ __launch_bounds__(TPB) void pairmin_kernel(
    const float* __restrict__ pred, const float* __restrict__ label,
    float* __restrict__ part, int N, int M) {
  const int dir = blockIdx.z;
  const float* __restrict__ q = dir ? label : pred;
  const float* __restrict__ r = dir ? pred : label;
  const int nq = dir ? M : N;
  const int nr = dir ? N : M;
  const int cs = nr / CH;  // 512

  __shared__ float4 sx[CS / 4], sy[CS / 4], sz[CS / 4];
  float* sxf = (float*)sx;
  float* syf = (float*)sy;
  float* szf = (float*)sz;

  const int t = threadIdx.x;

  // Stage this chunk's refs into LDS as SoA (x[], y[], z[]).
  const int rbase = blockIdx.y * cs;
  for (int k = t; k < cs * 3; k += TPB) {
    float v = r[rbase * 3 + k];
    int p = k / 3;
    int c = k - p * 3;
    if (c == 0) sxf[p] = v;
    else if (c == 1) syf[p] = v;
    else szf[p] = v;
  }
  __syncthreads();

  const int i = blockIdx.x * TPB + t;
  const float px = q[3 * i + 0];
  const float py = q[3 * i + 1];
  const float pz = q[3 * i + 2];

  // 4 independent min chains (break the v_min dependency).
  float m0 = 3.4e38f, m1 = 3.4e38f, m2 = 3.4e38f, m3 = 3.4e38f;
#pragma unroll 2
  for (int j = 0; j < cs / 4; ++j) {
    float4 X = sx[j], Y = sy[j], Z = sz[j];  // wave-uniform broadcast reads
    float dx, dy, dz, d;
    dx = px - X.x; dy = py - Y.x; dz = pz - Z.x;
    d = dx * dx + dy * dy + dz * dz; m0 = fminf(m0, d);
    dx = px - X.y; dy = py - Y.y; dz = pz - Z.y;
    d = dx * dx + dy * dy + dz * dz; m1 = fminf(m1, d);
    dx = px - X.z; dy = py - Y.z; dz = pz - Z.z;
    d = dx * dx + dy * dy + dz * dz; m2 = fminf(m2, d);
    dx = px - X.w; dy = py - Y.w; dz = pz - Z.w;
    d = dx * dx + dy * dy + dz * dz; m3 = fminf(m3, d);
  }
  float m = fminf(fminf(m0, m1), fminf(m2, m3));

  const size_t off = dir ? (size_t)CH * (size_t)N : 0;
  part[off + (size_t)blockIdx.y * (size_t)nq + i] = m;
}

// Kernel 2: per point, min over CH partials -> sqrt -> block sum.
// grid = N/TPB + M/TPB blocks; first N/TPB handle dir 0.
__global__ __launch_bounds__(TPB) void reduce_kernel(
    const float* __restrict__ part, float* __restrict__ bsums, int N, int M) {
  const int nbx = N / TPB;
  const int b = blockIdx.x;
  const int dir = (b >= nbx) ? 1 : 0;
  const int pb = dir ? (b - nbx) : b;
  const int nq = dir ? M : N;
  const size_t off = dir ? (size_t)CH * (size_t)N : 0;
  const int t = threadIdx.x;
  const int i = pb * TPB + t;

  float m = 3.4e38f;
#pragma unroll
  for (int c = 0; c < CH; ++c)
    m = fminf(m, part[off + (size_t)c * (size_t)nq + i]);
  float d = sqrtf(m);

  // block reduction: wave shuffle then LDS across the 4 waves
  for (int o = 32; o >= 1; o >>= 1) d += __shfl_down(d, o);
  __shared__ float wsum[TPB / 64];
  if ((t & 63) == 0) wsum[t >> 6] = d;
  __syncthreads();
  if (t == 0) {
    float s = 0.f;
#pragma unroll
    for (int w = 0; w < TPB / 64; ++w) s += wsum[w];
    bsums[b] = s;
  }
}

// Kernel 3: one wave sums the block sums and writes the scalar output.
__global__ void final_kernel(const float* __restrict__ bsums,
                             float* __restrict__ out,
                             int nbx, int nby, int N, int M) {
  const int t = threadIdx.x;  // 64 threads
  float v0 = (t < nbx) ? bsums[t] : 0.0f;
  float v1 = (t < nby) ? bsums[nbx + t] : 0.0f;
  for (int o = 32; o >= 1; o >>= 1) {
    v0 += __shfl_down(v0, o);
    v1 += __shfl_down(v1, o);
  }
  if (t == 0) out[0] = v0 / (float)N + v1 / (float)M;
}

extern "C" void kernel_launch(void* const* d_in, const int* in_sizes, int n_in,
                              void* d_out, int out_size, void* d_ws, size_t ws_size,
                              hipStream_t stream) {
  const float* pred  = (const float*)d_in[0];
  const float* label = (const float*)d_in[1];
  const int N = in_sizes[0] / 3;  // 8192
  const int M = in_sizes[1] / 3;  // 8192

  // workspace layout: part[CH*(N+M)] floats, then bsums[(N+M)/TPB]
  float* part  = (float*)d_ws;
  float* bsums = part + (size_t)CH * (size_t)(N + M);

  const int nbx = N / TPB;  // 32
  const int nby = M / TPB;  // 32

  // N == M for this problem, so one grid.x covers both directions.
  pairmin_kernel<<<dim3(nbx, CH, 2), TPB, 0, stream>>>(pred, label, part, N, M);
  reduce_kernel<<<nbx + nby, TPB, 0, stream>>>(part, bsums, N, M);
  final_kernel<<<1, 64, 0, stream>>>(bsums, (float*)d_out, nbx, nby, N, M);
}

// Round 2
// 81.810 us; speedup vs baseline: 1.0306x; 1.0306x over previous
//
#include <hip/hip_runtime.h>
#include <math.h>

#define TPB 256
#define QPT 4           // query points per thread
#define CH  64          // ref chunks per direction
#define CSR 128         // refs per chunk = 8192 / CH

// Kernel 1: each thread computes min squared distance of its 4 query points
// over one chunk of 128 refs.  grid = (N/(TPB*QPT), CH, 2).
// dir 0: query=pred, ref=label.  dir 1: swapped.
__global__ __launch_bounds__(TPB) void pairmin_kernel(
    const float* __restrict__ pred, const float* __restrict__ label,
    float* __restrict__ part, int N, int M) {
  const int dir = blockIdx.z;
  const float* __restrict__ q = dir ? label : pred;
  const float* __restrict__ r = dir ? pred : label;
  const int nq = dir ? M : N;
  const int nr = dir ? N : M;
  const int cs = nr / CH;  // 128

  // Raw AoS copy of this chunk's refs: cs*3 floats = cs*3/4 float4s.
  __shared__ float s[CSR * 3];
  const int t = threadIdx.x;
  if (t < (cs * 3) / 4)
    ((float4*)s)[t] = ((const float4*)(r + (size_t)blockIdx.y * cs * 3))[t];
  __syncthreads();

  // Load 4 consecutive query points (12 floats, 16B-aligned).
  const int i0 = (blockIdx.x * TPB + t) * QPT;
  const float4 Q0 = *(const float4*)(q + (size_t)i0 * 3 + 0);
  const float4 Q1 = *(const float4*)(q + (size_t)i0 * 3 + 4);
  const float4 Q2 = *(const float4*)(q + (size_t)i0 * 3 + 8);
  const float px[QPT] = {Q0.x, Q0.w, Q1.z, Q2.y};
  const float py[QPT] = {Q0.y, Q1.x, Q1.w, Q2.z};
  const float pz[QPT] = {Q0.z, Q1.y, Q2.x, Q2.w};

  float m[QPT] = {3.4e38f, 3.4e38f, 3.4e38f, 3.4e38f};

#pragma unroll 2
  for (int j = 0; j < cs / 4; ++j) {
    // 4 refs = 12 floats = 3 float4s (wave-uniform broadcast reads).
    const float4 A = ((const float4*)s)[3 * j + 0];
    const float4 B = ((const float4*)s)[3 * j + 1];
    const float4 C = ((const float4*)s)[3 * j + 2];
    const float rx[4] = {A.x, A.w, B.z, C.y};
    const float ry[4] = {A.y, B.x, B.w, C.z};
    const float rz[4] = {A.z, B.y, C.x, C.w};
#pragma unroll
    for (int rr = 0; rr < 4; ++rr) {
#pragma unroll
      for (int qq = 0; qq < QPT; ++qq) {
        const float dx = px[qq] - rx[rr];
        const float dy = py[qq] - ry[rr];
        const float dz = pz[qq] - rz[rr];
        const float d = dx * dx + dy * dy + dz * dz;
        m[qq] = fminf(m[qq], d);
      }
    }
  }

  const size_t off = dir ? (size_t)CH * (size_t)N : 0;
  *(float4*)&part[off + (size_t)blockIdx.y * nq + i0] =
      make_float4(m[0], m[1], m[2], m[3]);
}

// Kernel 2: per point, min over CH partials -> sqrt -> block sum.
// grid = N/TPB + M/TPB blocks; first N/TPB handle dir 0.
__global__ __launch_bounds__(TPB) void reduce_kernel(
    const float* __restrict__ part, float* __restrict__ bsums, int N, int M) {
  const int nbx = N / TPB;
  const int b = blockIdx.x;
  const int dir = (b >= nbx) ? 1 : 0;
  const int pb = dir ? (b - nbx) : b;
  const int nq = dir ? M : N;
  const size_t off = dir ? (size_t)CH * (size_t)N : 0;
  const int t = threadIdx.x;
  const int i = pb * TPB + t;

  float m = 3.4e38f;
#pragma unroll
  for (int c = 0; c < CH; ++c)
    m = fminf(m, part[off + (size_t)c * nq + i]);
  float d = sqrtf(m);

  for (int o = 32; o >= 1; o >>= 1) d += __shfl_down(d, o);
  __shared__ float wsum[TPB / 64];
  if ((t & 63) == 0) wsum[t >> 6] = d;
  __syncthreads();
  if (t == 0) {
    float sum = 0.f;
#pragma unroll
    for (int w = 0; w < TPB / 64; ++w) sum += wsum[w];
    bsums[b] = sum;
  }
}

// Kernel 3: one wave sums the block sums and writes the scalar output.
__global__ void final_kernel(const float* __restrict__ bsums,
                             float* __restrict__ out,
                             int nbx, int nby, int N, int M) {
  const int t = threadIdx.x;  // 64 threads
  float v0 = (t < nbx) ? bsums[t] : 0.0f;
  float v1 = (t < nby) ? bsums[nbx + t] : 0.0f;
  for (int o = 32; o >= 1; o >>= 1) {
    v0 += __shfl_down(v0, o);
    v1 += __shfl_down(v1, o);
  }
  if (t == 0) out[0] = v0 / (float)N + v1 / (float)M;
}

extern "C" void kernel_launch(void* const* d_in, const int* in_sizes, int n_in,
                              void* d_out, int out_size, void* d_ws, size_t ws_size,
                              hipStream_t stream) {
  const float* pred  = (const float*)d_in[0];
  const float* label = (const float*)d_in[1];
  const int N = in_sizes[0] / 3;  // 8192
  const int M = in_sizes[1] / 3;  // 8192

  // workspace: part[CH*(N+M)] floats, then bsums[(N+M)/TPB]
  float* part  = (float*)d_ws;
  float* bsums = part + (size_t)CH * (size_t)(N + M);

  const int nbx = N / TPB;  // 32
  const int nby = M / TPB;  // 32

  pairmin_kernel<<<dim3(N / (TPB * QPT), CH, 2), TPB, 0, stream>>>(
      pred, label, part, N, M);
  reduce_kernel<<<nbx + nby, TPB, 0, stream>>>(part, bsums, N, M);
  final_kernel<<<1, 64, 0, stream>>>(bsums, (float*)d_out, nbx, nby, N, M);
}

// Round 3
// 69.414 us; speedup vs baseline: 1.2147x; 1.1786x over previous
//
#include <hip/hip_runtime.h>
#include <math.h>

#define TPB 256
#define QPT 8           // query points per thread
#define CH  64          // ref chunks per direction
#define CSR 128         // refs per chunk = 8192 / CH

// Kernel 1: each thread holds 8 query points; for one chunk of 128 refs it
// computes t = max_r (p.r - ||r||^2/2)  (equivalent to min_r ||p-r||^2).
// grid = (N/(TPB*QPT), CH, 2).  dir 0: query=pred, ref=label.  dir 1: swapped.
__global__ __launch_bounds__(TPB) void pairmin_kernel(
    const float* __restrict__ pred, const float* __restrict__ label,
    float* __restrict__ part, int N, int M) {
  const int dir = blockIdx.z;
  const float* __restrict__ q = dir ? label : pred;
  const float* __restrict__ r = dir ? pred : label;
  const int nq = dir ? M : N;
  const int nr = dir ? N : M;
  const int cs = nr / CH;  // 128

  // LDS: one float4 per ref = [x, y, z, ||r||^2 / 2]
  __shared__ float4 s[CSR];
  const int t = threadIdx.x;
  if (t < cs) {
    const float* rp = r + ((size_t)blockIdx.y * cs + t) * 3;
    const float rx = rp[0], ry = rp[1], rz = rp[2];
    s[t] = make_float4(rx, ry, rz, 0.5f * (rx * rx + ry * ry + rz * rz));
  }
  __syncthreads();

  // Load 8 consecutive query points (24 floats = 6 float4s, 16B-aligned).
  const int i0 = (blockIdx.x * TPB + t) * QPT;
  float px[QPT], py[QPT], pz[QPT], m[QPT];
  {
    const float4* qv = (const float4*)(q + (size_t)i0 * 3);
    float c[24];
#pragma unroll
    for (int v = 0; v < 6; ++v) {
      float4 f = qv[v];
      c[4 * v + 0] = f.x; c[4 * v + 1] = f.y; c[4 * v + 2] = f.z; c[4 * v + 3] = f.w;
    }
#pragma unroll
    for (int qq = 0; qq < QPT; ++qq) {
      px[qq] = c[3 * qq + 0];
      py[qq] = c[3 * qq + 1];
      pz[qq] = c[3 * qq + 2];
      m[qq] = -3.4e38f;
    }
  }

#pragma unroll 2
  for (int j = 0; j < cs / 4; ++j) {
    float4 R[4];
#pragma unroll
    for (int rr = 0; rr < 4; ++rr) R[rr] = s[4 * j + rr];
#pragma unroll
    for (int rr = 0; rr < 4; ++rr) {
#pragma unroll
      for (int qq = 0; qq < QPT; ++qq) {
        // t = p.r - hr  (3 FMA), then running max
        float v = fmaf(pz[qq], R[rr].z, -R[rr].w);
        v = fmaf(py[qq], R[rr].y, v);
        v = fmaf(px[qq], R[rr].x, v);
        m[qq] = fmaxf(m[qq], v);
      }
    }
  }

  const size_t off = dir ? (size_t)CH * (size_t)N : 0;
  float* dst = &part[off + (size_t)blockIdx.y * nq + i0];
  *(float4*)(dst + 0) = make_float4(m[0], m[1], m[2], m[3]);
  *(float4*)(dst + 4) = make_float4(m[4], m[5], m[6], m[7]);
}

// Kernel 2: per point, max over CH partials -> d = sqrt(max(0, ||p||^2 - 2*t))
// -> block sum.  grid = N/TPB + M/TPB blocks; first N/TPB handle dir 0.
__global__ __launch_bounds__(TPB) void reduce_kernel(
    const float* __restrict__ pred, const float* __restrict__ label,
    const float* __restrict__ part, float* __restrict__ bsums, int N, int M) {
  const int nbx = N / TPB;
  const int b = blockIdx.x;
  const int dir = (b >= nbx) ? 1 : 0;
  const int pb = dir ? (b - nbx) : b;
  const int nq = dir ? M : N;
  const float* __restrict__ q = dir ? label : pred;
  const size_t off = dir ? (size_t)CH * (size_t)N : 0;
  const int t = threadIdx.x;
  const int i = pb * TPB + t;

  float m = -3.4e38f;
#pragma unroll
  for (int c = 0; c < CH; ++c)
    m = fmaxf(m, part[off + (size_t)c * nq + i]);

  const float qx = q[3 * i + 0], qy = q[3 * i + 1], qz = q[3 * i + 2];
  const float pp = qx * qx + qy * qy + qz * qz;
  float d = sqrtf(fmaxf(0.0f, fmaf(-2.0f, m, pp)));

  for (int o = 32; o >= 1; o >>= 1) d += __shfl_down(d, o);
  __shared__ float wsum[TPB / 64];
  if ((t & 63) == 0) wsum[t >> 6] = d;
  __syncthreads();
  if (t == 0) {
    float sum = 0.f;
#pragma unroll
    for (int w = 0; w < TPB / 64; ++w) sum += wsum[w];
    bsums[b] = sum;
  }
}

// Kernel 3: one wave sums the block sums and writes the scalar output.
__global__ void final_kernel(const float* __restrict__ bsums,
                             float* __restrict__ out,
                             int nbx, int nby, int N, int M) {
  const int t = threadIdx.x;  // 64 threads
  float v0 = (t < nbx) ? bsums[t] : 0.0f;
  float v1 = (t < nby) ? bsums[nbx + t] : 0.0f;
  for (int o = 32; o >= 1; o >>= 1) {
    v0 += __shfl_down(v0, o);
    v1 += __shfl_down(v1, o);
  }
  if (t == 0) out[0] = v0 / (float)N + v1 / (float)M;
}

extern "C" void kernel_launch(void* const* d_in, const int* in_sizes, int n_in,
                              void* d_out, int out_size, void* d_ws, size_t ws_size,
                              hipStream_t stream) {
  const float* pred  = (const float*)d_in[0];
  const float* label = (const float*)d_in[1];
  const int N = in_sizes[0] / 3;  // 8192
  const int M = in_sizes[1] / 3;  // 8192

  // workspace: part[CH*(N+M)] floats, then bsums[(N+M)/TPB]
  float* part  = (float*)d_ws;
  float* bsums = part + (size_t)CH * (size_t)(N + M);

  const int nbx = N / TPB;  // 32
  const int nby = M / TPB;  // 32

  pairmin_kernel<<<dim3(N / (TPB * QPT), CH, 2), TPB, 0, stream>>>(
      pred, label, part, N, M);
  reduce_kernel<<<nbx + nby, TPB, 0, stream>>>(pred, label, part, bsums, N, M);
  final_kernel<<<1, 64, 0, stream>>>(bsums, (float*)d_out, nbx, nby, N, M);
}